// Round 5
// baseline (4635.456 us; speedup 1.0000x reference)
//
#include <hip/hip_runtime.h>

#define T_SEQ 1024
#define NBATCH 256
#define DIN 128
#define HID 64
#define DOUT 128

// ---------------- LDS layout (256-thread, full-K, uniform-broadcast) ----------------
// Encoder buffer (256 floats): X @0(128) | H0 @128(64) | H1 @192(64)
//   L0 input = [x|h0] = floats [0..192) contiguous; L1 input = [h0|h1] = [128..256).
// Decoder overlay (192 floats): H1A @0(64) | H0 @64(64) | H1B @128(64)
//   L0 input = [h1|h0] = [0..128); L1 input = h0new @W[64..128) + h1old @R[128..192); fc = [0..64).
#define LOG2E_F 1.4426950408889634f
#define TWO_LOG2E 2.8853900817779268f   // 2*log2(e)

typedef float v2f __attribute__((ext_vector_type(2)));

__device__ __forceinline__ float rcp_f(float x) { return __builtin_amdgcn_rcpf(x); }

__device__ __forceinline__ float exp2_f(float x) {
#if __has_builtin(__builtin_amdgcn_exp2f)
  return __builtin_amdgcn_exp2f(x);
#else
  return exp2f(x);
#endif
}

// tanh(x) with pre-scaled argument y = x*TWO_LOG2E:  tanh = 1 - 2/(1+2^y); inf-safe
__device__ __forceinline__ float tanh_pre(float y) {
  float m = exp2_f(y);
  return fmaf(-2.0f, rcp_f(1.0f + m), 1.0f);
}
__device__ __forceinline__ float tanh_full(float x) { return tanh_pre(x * TWO_LOG2E); }

// DPP mov row_shl:N (0x100|N): dst lane i <- src lane i+N within 16-lane row (OOB -> 0)
template<int CTRL>
__device__ __forceinline__ float dpp_mov(float v) {
  int p = __builtin_amdgcn_update_dpp(0, __float_as_int(v), CTRL, 0xF, 0xF, true);
  return __int_as_float(p);
}

// LDS-only barrier: do NOT drain vmcnt (x prefetch loads / out stores stay in flight).
__device__ __forceinline__ void bar_lds() {
  asm volatile("s_waitcnt lgkmcnt(0)\n\ts_barrier" ::: "memory");
}

template<int N4>
__device__ __forceinline__ void loadrow(float* w, const float* p) {
#pragma unroll
  for (int k = 0; k < N4; ++k) {
    float4 q = ((const float4*)p)[k];
    w[4*k+0] = q.x; w[4*k+1] = q.y; w[4*k+2] = q.z; w[4*k+3] = q.w;
  }
}

// Fused 2-row packed dot: ONE activation read feeds BOTH rows (halves LDS instrs).
template<int K4>
__device__ __forceinline__ void dot2(const float* wa, const float* wb, const float4* v,
                                     float& ra, float& rb) {
  const v2f* A = (const v2f*)wa;
  const v2f* B = (const v2f*)wb;
  v2f a0 = {0.f,0.f}, a1 = {0.f,0.f}, b0 = {0.f,0.f}, b1 = {0.f,0.f};
#pragma unroll
  for (int k = 0; k < K4; ++k) {
    float4 q = v[k];
    v2f q0 = {q.x, q.y};
    v2f q1 = {q.z, q.w};
    a0 = __builtin_elementwise_fma(A[2*k+0], q0, a0);
    a1 = __builtin_elementwise_fma(A[2*k+1], q1, a1);
    b0 = __builtin_elementwise_fma(B[2*k+0], q0, b0);
    b1 = __builtin_elementwise_fma(B[2*k+1], q1, b1);
  }
  v2f sa = a0 + a1, sb = b0 + b1;
  ra = sa.x + sa.y;
  rb = sb.x + sb.y;
}

// Single-row packed dot (fc)
template<int K4>
__device__ __forceinline__ float dotp(const float* wf, const float4* v) {
  const v2f* w = (const v2f*)wf;
  v2f a0 = {0.f,0.f}, a1 = {0.f,0.f};
#pragma unroll
  for (int k = 0; k < K4; ++k) {
    float4 q = v[k];
    v2f q0 = {q.x, q.y};
    v2f q1 = {q.z, q.w};
    a0 = __builtin_elementwise_fma(w[2*k+0], q0, a0);
    a1 = __builtin_elementwise_fma(w[2*k+1], q1, a1);
  }
  v2f s = a0 + a1;
  return s.x + s.y;
}

// Thread pair (p=0: rows {i,f}; p=1: rows {g,o}) of one unit u.
// pa -> i (p=0) / g~ (p=1); pb -> f / o (sigmoid always).
// Exchange g~,o from lane+1 via row_shl:1. c,h valid on EVEN lanes only.
__device__ __forceinline__ float cell2(float pa, float pb, float gscA, float gsclA, float gofA,
                                       float& c) {
  float va = fmaf(gscA, tanh_pre(pa * gsclA), gofA);   // i or g~
  float vb = fmaf(0.5f, tanh_pre(pb * LOG2E_F), 0.5f); // f or o (sigmoid)
  float gT = dpp_mov<0x101>(va);                       // even lane: g~
  float oS = dpp_mov<0x101>(vb);                       // even lane: o
  c = fmaf(vb, c, va * gT);                            // f*c + i*g~
  return oS * tanh_full(c);
}

// ---------------- prep kernel: C0 = dWih0 @ fcW  [256x64], fcbt = dWih0 @ fcb ----------------
__global__ void prep_kernel(const float* __restrict__ dWih0,
                            const float* __restrict__ fcW,
                            const float* __restrict__ fcb,
                            float* __restrict__ ws) {
  const int r = (int)blockIdx.x;           // 256 blocks
  const int jj = (int)threadIdx.x;         // 64 threads
  const float* wr = dWih0 + (size_t)r * DIN;
  float acc = 0.f;
  for (int o = 0; o < DIN; ++o) acc = fmaf(wr[o], fcW[(size_t)o * HID + jj], acc);
  ws[(size_t)r * HID + jj] = acc;
  if (jj == 0) {
    float a = 0.f;
    for (int o = 0; o < DIN; ++o) a = fmaf(wr[o], fcb[o], a);
    ws[256 * HID + r] = a;
  }
}

// ---------------- main persistent kernel: 1 block / batch element, 256 threads ----------------
__global__ __launch_bounds__(256, 1) void lstm_ae_kernel(
    const float* __restrict__ x,
    const float* __restrict__ eW0, const float* __restrict__ eU0,
    const float* __restrict__ ebi0, const float* __restrict__ ebh0,
    const float* __restrict__ eW1, const float* __restrict__ eU1,
    const float* __restrict__ ebi1, const float* __restrict__ ebh1,
    const float* __restrict__ dW0, const float* __restrict__ dU0,
    const float* __restrict__ dbi0, const float* __restrict__ dbh0,
    const float* __restrict__ dW1, const float* __restrict__ dU1,
    const float* __restrict__ dbi1, const float* __restrict__ dbh1,
    const float* __restrict__ fcW, const float* __restrict__ fcb,
    const float* __restrict__ ws,
    float* __restrict__ out)
{
  __shared__ __align__(16) float Abuf[256];
  __shared__ __align__(16) float Bbuf[256];

  const int tid = (int)threadIdx.x;
  const int b   = (int)blockIdx.x;
  const int p   = tid & 1;

  const float gscA  = p ? 1.0f : 0.5f;        // row-A nonlin: sigmoid(i) / tanh(g)
  const float gofA  = p ? 0.0f : 0.5f;
  const float gsclA = p ? TWO_LOG2E : LOG2E_F;

  const float* xb   = x + (size_t)b * (T_SEQ * DIN);
  float* outb       = out + (size_t)b * (T_SEQ * DOUT);

  // init LDS: Abuf: x_0 | h0(-1)=0 | h1(-2)=0 ; Bbuf: h1(-1)=0
  if (tid < 32) {
    float4 v = ((const float4*)xb)[tid];
    ((float4*)Abuf)[tid] = v;
  }
  if (tid >= 128) Abuf[tid] = 0.f;
  if (tid >= 192) Bbuf[tid] = 0.f;
  __syncthreads();

  if (tid < 128) {
    // ================= ROLE 0: layer-0 (waves 0,1) =================
    const int u  = tid >> 1;
    const int rA = (2 * p) * HID + u;        // i or g row
    const int rB = (2 * p + 1) * HID + u;    // f or o row
    float w[384];

    // enc L0 rows: [eW0_r(128) | eU0_r(64)] matches LDS [x|h0]
    loadrow<32>(w,       eW0 + (size_t)rA * DIN);
    loadrow<16>(w + 128, eU0 + (size_t)rA * HID);
    loadrow<32>(w + 192, eW0 + (size_t)rB * DIN);
    loadrow<16>(w + 320, eU0 + (size_t)rB * HID);
    float bsA = ebi0[rA] + ebh0[rA];
    float bsB = ebi0[rB] + ebh0[rB];
    float c = 0.f;

    auto enc_phase = [&](float* R, float* W, int t) {
      float4 xn;
      const bool pf = (tid < 32) && (t + 1 < T_SEQ);
      if (pf) xn = ((const float4*)(xb + (size_t)(t + 1) * DIN))[tid];
      float pa, pb;
      dot2<48>(w, w + 192, (const float4*)R, pa, pb);   // [x|h0] = R[0..192)
      pa += bsA; pb += bsB;
      float h = cell2(pa, pb, gscA, gsclA, gofA, c);
      if (p == 0) W[128 + u] = h;                       // h0(t)
      if (pf) ((float4*)W)[tid] = xn;                   // stage x_{t+1}
      bar_lds();
    };
#pragma unroll 1
    for (int t = 0; t < T_SEQ; t += 2) {
      enc_phase(Abuf, Bbuf, t);
      enc_phase(Bbuf, Abuf, t + 1);
    }
    bar_lds();            // matches role1 epilogue barrier
    __syncthreads();      // T1: h1(1023) visible in Abuf

    // transition: tanh h0enc (tid<64) / h1enc (tid 64..127); both read Abuf[128+tid]
    float hv = tanh_full(Abuf[128 + tid]);
    c = tanh_full(c);     // dec c0 init (even lanes meaningful)
    __syncthreads();      // T2: reads done
    Abuf[64 + tid] = hv;  // tid<64 -> H0 @[64..128); tid>=64 -> H1B @[128..192)
    __syncthreads();      // T3

    // dec L0 rows: [C0_r(64) | dU0_r(64)] matches LDS [H1A|H0] = [0..128)
    const float* C0 = ws;
    const float* fcbt_arr = ws + 256 * HID;
    loadrow<16>(w,       C0  + (size_t)rA * HID);
    loadrow<16>(w + 64,  dU0 + (size_t)rA * HID);
    loadrow<16>(w + 128, C0  + (size_t)rB * HID);
    loadrow<16>(w + 192, dU0 + (size_t)rB * HID);
    bsA = dbi0[rA] + dbh0[rA];
    bsB = dbi0[rB] + dbh0[rB];
    const float ftA = fcbt_arr[rA];
    const float ftB = fcbt_arr[rB];

    auto dec_step = [&](float* R_, float* W_, int t) {
      float pa, pb;
      dot2<32>(w, w + 128, (const float4*)R_, pa, pb);  // [h1|h0] = R_[0..128)
      pa += bsA; pb += bsB;
      if (t > 0) { pa += ftA; pb += ftB; }              // composite fcb (absent at t=0)
      float h = cell2(pa, pb, gscA, gsclA, gofA, c);
      if (p == 0) W_[64 + u] = h;                       // h0(t)
      bar_lds();                                        // phase A
      bar_lds();                                        // phase B (role0 idle)
    };
#pragma unroll 1
    for (int t = 0; t < T_SEQ; t += 2) {
      dec_step(Abuf, Bbuf, t);
      dec_step(Bbuf, Abuf, t + 1);
    }
  } else {
    // ================= ROLE 1: layer-1 + fc (waves 2,3) =================
    const int u  = (tid - 128) >> 1;
    const int rA = (2 * p) * HID + u;
    const int rB = (2 * p + 1) * HID + u;
    float w[256];
    float fw[64];

    // enc L1 rows: [eW1_r(64) | eU1_r(64)] matches LDS [h0|h1] = [128..256)
    loadrow<16>(w,       eW1 + (size_t)rA * HID);
    loadrow<16>(w + 64,  eU1 + (size_t)rA * HID);
    loadrow<16>(w + 128, eW1 + (size_t)rB * HID);
    loadrow<16>(w + 192, eU1 + (size_t)rB * HID);
    float bsA = ebi1[rA] + ebh1[rA];
    float bsB = ebi1[rB] + ebh1[rB];
    float c = 0.f;

    auto enc_phase = [&](float* R, float* W, int t) {
      float pa, pb;
      dot2<32>(w, w + 128, (const float4*)(R + 128), pa, pb);  // [h0(t-1)|h1(t-2)]
      pa += bsA; pb += bsB;
      float cn = c;
      float h = cell2(pa, pb, gscA, gsclA, gofA, cn);
      if (t > 0) {                       // t=0: h1(-1)/c1 stay at zero init
        c = cn;
        if (p == 0) W[192 + u] = h;      // h1(t-1)
      }
      bar_lds();
    };
#pragma unroll 1
    for (int t = 0; t < T_SEQ; t += 2) {
      enc_phase(Abuf, Bbuf, t);
      enc_phase(Bbuf, Abuf, t + 1);
    }
    // epilogue: h1(1023) from Abuf [h0(1023)|h1(1022)]
    {
      float pa, pb;
      dot2<32>(w, w + 128, (const float4*)(Abuf + 128), pa, pb);
      pa += bsA; pb += bsB;
      float h = cell2(pa, pb, gscA, gsclA, gofA, c);
      bar_lds();                         // all reads of old h1 slot done before overwrite
      if (p == 0) Abuf[192 + u] = h;
    }
    __syncthreads();      // T1
    c = tanh_full(c);     // dec c1 init
    __syncthreads();      // T2
    if (tid < 192) Abuf[tid - 128] = 0.f;   // H1A @[0..64) = 0 (t=0: pred_{-1}=0)
    __syncthreads();      // T3

    // dec L1 rows: [dW1_r(64) | dU1_r(64)]; fc row oo
    loadrow<16>(w,       dW1 + (size_t)rA * HID);
    loadrow<16>(w + 64,  dU1 + (size_t)rA * HID);
    loadrow<16>(w + 128, dW1 + (size_t)rB * HID);
    loadrow<16>(w + 192, dU1 + (size_t)rB * HID);
    bsA = dbi1[rA] + dbh1[rA];
    bsB = dbi1[rB] + dbh1[rB];
    const int oo = tid - 128;            // fc output index [0,128)
    loadrow<16>(fw, fcW + (size_t)oo * HID);
    const float fb = fcb[oo];

    auto dec_step = [&](float* R_, float* W_, int t) {
      // phase A: fc for pred_{t-1} from h1(t-1) @ R_[0..64)
      float s = dotp<16>(fw, (const float4*)R_);
      if (t > 0) outb[(size_t)(t - 1) * DOUT + oo] = s + fb;
      bar_lds();                                        // phase A: h0(t) now visible
      // phase B: h1(t) from [h0(t) @ W_[64..128) | h1(t-1) @ R_[128..192)]
      float pa1, pb1, pa2, pb2;
      dot2<16>(w,      w + 128, (const float4*)(W_ + 64),  pa1, pb1);
      dot2<16>(w + 64, w + 192, (const float4*)(R_ + 128), pa2, pb2);
      float pa = pa1 + pa2 + bsA;
      float pb = pb1 + pb2 + bsB;
      float h = cell2(pa, pb, gscA, gsclA, gofA, c);
      if (p == 0) { W_[u] = h; W_[128 + u] = h; }       // H1A + H1B
      bar_lds();                                        // phase B
    };
#pragma unroll 1
    for (int t = 0; t < T_SEQ; t += 2) {
      dec_step(Abuf, Bbuf, t);
      dec_step(Bbuf, Abuf, t + 1);
    }
    // epilogue: pred_{1023} from h1(1023) @ Abuf[0..64)
    float s = dotp<16>(fw, (const float4*)Abuf);
    outb[(size_t)(T_SEQ - 1) * DOUT + oo] = s + fb;
  }
}

extern "C" void kernel_launch(void* const* d_in, const int* in_sizes, int n_in,
                              void* d_out, int out_size, void* d_ws, size_t ws_size,
                              hipStream_t stream) {
  (void)in_sizes; (void)n_in; (void)ws_size; (void)out_size;
  const float* x    = (const float*)d_in[0];
  const float* eW0  = (const float*)d_in[1];
  const float* eU0  = (const float*)d_in[2];
  const float* ebi0 = (const float*)d_in[3];
  const float* ebh0 = (const float*)d_in[4];
  const float* eW1  = (const float*)d_in[5];
  const float* eU1  = (const float*)d_in[6];
  const float* ebi1 = (const float*)d_in[7];
  const float* ebh1 = (const float*)d_in[8];
  const float* dW0  = (const float*)d_in[9];
  const float* dU0  = (const float*)d_in[10];
  const float* dbi0 = (const float*)d_in[11];
  const float* dbh0 = (const float*)d_in[12];
  const float* dW1  = (const float*)d_in[13];
  const float* dU1  = (const float*)d_in[14];
  const float* dbi1 = (const float*)d_in[15];
  const float* dbh1 = (const float*)d_in[16];
  const float* fcW  = (const float*)d_in[17];
  const float* fcb  = (const float*)d_in[18];
  float* ws  = (float*)d_ws;
  float* out = (float*)d_out;

  hipLaunchKernelGGL(prep_kernel, dim3(256), dim3(64), 0, stream, dW0, fcW, fcb, ws);
  hipLaunchKernelGGL(lstm_ae_kernel, dim3(NBATCH), dim3(256), 0, stream,
                     x, eW0, eU0, ebi0, ebh0, eW1, eU1, ebi1, ebh1,
                     dW0, dU0, dbi0, dbh0, dW1, dU1, dbi1, dbh1,
                     fcW, fcb, ws, out);
}

// Round 6
// 2027.564 us; speedup vs baseline: 2.2862x; 2.2862x over previous
//
#include <hip/hip_runtime.h>

#define T_SEQ 1024
#define NBATCH 256
#define DIN 128
#define HID 64
#define DOUT 128

// ---------------- LDS layouts (512 thr, fused shared-chunk reads, single copies) ----------------
// Encoder buffer (256 floats): X @0(128) | H0 @128(64) | H1 @192(64)
//   thread reads its q-half of each chunk; h0 chunk feeds BOTH L0 and L1 dots.
// Decoder overlay (128 floats): H1 @0(64) | H0 @64(64)
//   phase A reads H1 (feeds C0-dot, dU1-partial, fc); phase B reads H0 (feeds dW1-dot, dU0-partial).
#define TWO_LOG2E 2.8853900817779268f   // 2*log2(e)

typedef float v2f __attribute__((ext_vector_type(2)));

__device__ __forceinline__ float rcp_f(float x) { return __builtin_amdgcn_rcpf(x); }

__device__ __forceinline__ float exp2_f(float x) {
#if __has_builtin(__builtin_amdgcn_exp2f)
  return __builtin_amdgcn_exp2f(x);
#else
  return exp2f(x);
#endif
}

// tanh(x) with pre-scaled argument y = x*TWO_LOG2E:  tanh = 1 - 2/(1+2^y); inf-safe
__device__ __forceinline__ float tanh_pre(float y) {
  float m = exp2_f(y);
  return fmaf(-2.0f, rcp_f(1.0f + m), 1.0f);
}
__device__ __forceinline__ float tanh_full(float x) { return tanh_pre(x * TWO_LOG2E); }

// quad-perm DPP butterfly add (lane^1: 0xB1) on the VALU pipe
template<int CTRL>
__device__ __forceinline__ float dpp_add(float v) {
  int p = __builtin_amdgcn_update_dpp(0, __float_as_int(v), CTRL, 0xF, 0xF, true);
  return v + __int_as_float(p);
}

// DPP mov row_shl:N (0x100|N): dst lane i <- src lane i+N within 16-lane row
template<int CTRL>
__device__ __forceinline__ float dpp_mov(float v) {
  int p = __builtin_amdgcn_update_dpp(0, __float_as_int(v), CTRL, 0xF, 0xF, true);
  return __int_as_float(p);
}

// LDS-only barrier: do NOT drain vmcnt (x prefetch loads / out stores stay in flight).
__device__ __forceinline__ void bar_lds() {
  asm volatile("s_waitcnt lgkmcnt(0)\n\ts_barrier" ::: "memory");
}

template<int N4>
__device__ __forceinline__ void loadrow(float* w, const float* p) {
#pragma unroll
  for (int k = 0; k < N4; ++k) {
    float4 q = ((const float4*)p)[k];
    w[4*k+0] = q.x; w[4*k+1] = q.y; w[4*k+2] = q.z; w[4*k+3] = q.w;
  }
}

// Lane map: q = tid&1 (k-half), g = (tid>>1)&3 (gate i,f,g,o), j = tid>>3 (unit).
// After the q-butterfly (xor1), 8-lane group holds: lanes 0,1=i; 2,3=f; 4,5=g~; 6,7=o.
// Gather f/g~/o into lanes 0,1 with row_shl:2/4/6. c/h valid on lanes 0,1 of each group.
__device__ __forceinline__ float cell_update(float pre, float gsc, float gscl, float gof, float& c) {
  float a  = fmaf(gsc, tanh_pre(pre * gscl), gof);  // sigmoid for i,f,o ; tanh for g
  float f_s = dpp_mov<0x102>(a);
  float g_t = dpp_mov<0x104>(a);
  float o_s = dpp_mov<0x106>(a);
  c = fmaf(f_s, c, a * g_t);
  return o_s * tanh_full(c);
}

// ---------------- prep kernel: C0 = dWih0 @ fcW  [256x64], fcbt = dWih0 @ fcb ----------------
__global__ void prep_kernel(const float* __restrict__ dWih0,
                            const float* __restrict__ fcW,
                            const float* __restrict__ fcb,
                            float* __restrict__ ws) {
  const int r = (int)blockIdx.x;           // 256 blocks
  const int jj = (int)threadIdx.x;         // 64 threads
  const float* wr = dWih0 + (size_t)r * DIN;
  float acc = 0.f;
  for (int o = 0; o < DIN; ++o) acc = fmaf(wr[o], fcW[(size_t)o * HID + jj], acc);
  ws[(size_t)r * HID + jj] = acc;
  if (jj == 0) {
    float a = 0.f;
    for (int o = 0; o < DIN; ++o) a = fmaf(wr[o], fcb[o], a);
    ws[256 * HID + r] = a;
  }
}

// ---------------- main persistent kernel: 1 block / batch element, 512 threads ----------------
__global__ __launch_bounds__(512, 2) void lstm_ae_kernel(
    const float* __restrict__ x,
    const float* __restrict__ eW0, const float* __restrict__ eU0,
    const float* __restrict__ ebi0, const float* __restrict__ ebh0,
    const float* __restrict__ eW1, const float* __restrict__ eU1,
    const float* __restrict__ ebi1, const float* __restrict__ ebh1,
    const float* __restrict__ dW0, const float* __restrict__ dU0,
    const float* __restrict__ dbi0, const float* __restrict__ dbh0,
    const float* __restrict__ dW1, const float* __restrict__ dU1,
    const float* __restrict__ dbi1, const float* __restrict__ dbh1,
    const float* __restrict__ fcW, const float* __restrict__ fcb,
    const float* __restrict__ ws,
    float* __restrict__ out)
{
  __shared__ __align__(16) float Abuf[256];
  __shared__ __align__(16) float Bbuf[256];

  const int tid = (int)threadIdx.x;
  const int b   = (int)blockIdx.x;
  const int q   = tid & 1;
  const int g   = (tid >> 1) & 3;
  const int j   = tid >> 3;
  const int r   = g * HID + j;
  const int l8  = tid & 7;
  const int fco = (tid >> 1) & 127;                    // fc output row (2x replicated)
  const bool fcwr = ((tid & 1) == 0) && (tid < 256);   // unique fc writer lanes

  const float gsc  = (g == 2) ? 1.0f : 0.5f;
  const float gof  = (g == 2) ? 0.0f : 0.5f;
  const float gscl = gsc * TWO_LOG2E;

  float w[160];

  // ---------------- encoder weights (q-half of each K-chunk, 1 row/thread) ----------------
  loadrow<16>(w,       eW0 + (size_t)r * DIN + q * 64);  // L0 x-part   (64)
  loadrow<8> (w + 64,  eU0 + (size_t)r * HID + q * 32);  // L0 h0-part  (32)
  loadrow<8> (w + 96,  eW1 + (size_t)r * HID + q * 32);  // L1 h0-part  (32)
  loadrow<8> (w + 128, eU1 + (size_t)r * HID + q * 32);  // L1 h1-part  (32)
  float bs0 = ebi0[r] + ebh0[r];
  float bs1 = ebi1[r] + ebh1[r];

  const float* xb = x + (size_t)b * (T_SEQ * DIN);
  float* outb     = out + (size_t)b * (T_SEQ * DOUT);

  // init: A = [x0 | h0(-1)=0 | h1(-2)=0]; B.H1 = h1(-1) = 0
  if (tid < 32) ((float4*)Abuf)[tid] = ((const float4*)xb)[tid];
  if (tid >= 128 && tid < 256) Abuf[tid] = 0.f;
  if (tid >= 192 && tid < 256) Bbuf[tid] = 0.f;
  float4 xcar{};
  if (tid < 32) xcar = ((const float4*)(xb + DIN))[tid];   // x(1) in flight
  float c0 = 0.f, c1 = 0.f;
  __syncthreads();

  // ---------------- phase 1: layer-skewed fused encoder (ONE barrier per phase) ----------------
  auto enc_phase = [&](float* R, float* W, int t) {
    if (tid < 32 && t + 1 < T_SEQ) ((float4*)W)[tid] = xcar;       // stage x(t+1) (vmcnt slack: 1 phase)
    if (tid < 32 && t + 2 < T_SEQ)
      xcar = ((const float4*)(xb + (size_t)(t + 2) * DIN))[tid];   // issue x(t+2)
    const float4* R4 = (const float4*)R;
    const v2f* wx  = (const v2f*)(w);
    const v2f* wh  = (const v2f*)(w + 64);
    const v2f* w1h = (const v2f*)(w + 96);
    const v2f* w1g = (const v2f*)(w + 128);
    v2f p0a = {0.f,0.f}, p0b = {0.f,0.f}, p1a = {0.f,0.f}, p1b = {0.f,0.f};
#pragma unroll
    for (int k = 0; k < 16; ++k) {                                  // x chunk (L0 only)
      float4 qv = R4[q * 16 + k]; v2f q0 = {qv.x, qv.y}, q1 = {qv.z, qv.w};
      p0a = __builtin_elementwise_fma(wx[2*k],   q0, p0a);
      p0b = __builtin_elementwise_fma(wx[2*k+1], q1, p0b);
    }
#pragma unroll
    for (int k = 0; k < 8; ++k) {                                   // h0 chunk (L0 AND L1, shared read)
      float4 qv = R4[32 + q * 8 + k]; v2f q0 = {qv.x, qv.y}, q1 = {qv.z, qv.w};
      p0a = __builtin_elementwise_fma(wh[2*k],    q0, p0a);
      p0b = __builtin_elementwise_fma(wh[2*k+1],  q1, p0b);
      p1a = __builtin_elementwise_fma(w1h[2*k],   q0, p1a);
      p1b = __builtin_elementwise_fma(w1h[2*k+1], q1, p1b);
    }
#pragma unroll
    for (int k = 0; k < 8; ++k) {                                   // h1 chunk (L1 only)
      float4 qv = R4[48 + q * 8 + k]; v2f q0 = {qv.x, qv.y}, q1 = {qv.z, qv.w};
      p1a = __builtin_elementwise_fma(w1g[2*k],   q0, p1a);
      p1b = __builtin_elementwise_fma(w1g[2*k+1], q1, p1b);
    }
    v2f s0 = p0a + p0b, s1 = p1a + p1b;
    float p0 = dpp_add<0xB1>(s0.x + s0.y) + bs0;
    float p1 = dpp_add<0xB1>(s1.x + s1.y) + bs1;
    float h0v = cell_update(p0, gsc, gscl, gof, c0);
    float c1n = c1;
    float h1v = cell_update(p1, gsc, gscl, gof, c1n);
    if (l8 == 0) W[128 + j] = h0v;                 // h0(t)
    if (t > 0) {                                   // t=0: h1(-1)/c1 stay at zero init
      c1 = c1n;
      if (l8 == 1) W[192 + j] = h1v;               // h1(t-1)
    }
    bar_lds();
  };

#pragma unroll 1
  for (int t = 0; t < T_SEQ; t += 2) {
    enc_phase(Abuf, Bbuf, t);
    enc_phase(Bbuf, Abuf, t + 1);
  }
  // encoder epilogue: h1(1023) from A = [h0(1023) | h1(1022)]
  {
    const float4* R4 = (const float4*)Abuf;
    const v2f* w1h = (const v2f*)(w + 96);
    const v2f* w1g = (const v2f*)(w + 128);
    v2f p1a = {0.f,0.f}, p1b = {0.f,0.f};
#pragma unroll
    for (int k = 0; k < 8; ++k) {
      float4 qv = R4[32 + q * 8 + k]; v2f q0 = {qv.x, qv.y}, q1 = {qv.z, qv.w};
      p1a = __builtin_elementwise_fma(w1h[2*k],   q0, p1a);
      p1b = __builtin_elementwise_fma(w1h[2*k+1], q1, p1b);
    }
#pragma unroll
    for (int k = 0; k < 8; ++k) {
      float4 qv = R4[48 + q * 8 + k]; v2f q0 = {qv.x, qv.y}, q1 = {qv.z, qv.w};
      p1a = __builtin_elementwise_fma(w1g[2*k],   q0, p1a);
      p1b = __builtin_elementwise_fma(w1g[2*k+1], q1, p1b);
    }
    v2f s1 = p1a + p1b;
    float p1 = dpp_add<0xB1>(s1.x + s1.y) + bs1;
    float h1v = cell_update(p1, gsc, gscl, gof, c1);
    bar_lds();                                     // reads of old h1 slot done before overwrite
    if (l8 == 0) Abuf[192 + j] = h1v;
  }
  __syncthreads();

  // ---------------- transition: decoder weights + state re-layout ----------------
  const float* C0 = ws;
  const float* fcbt_arr = ws + 256 * HID;
  loadrow<8>(w,       C0  + (size_t)r * HID + q * 32);   // L0 h1-part (composite C0)
  loadrow<8>(w + 32,  dU0 + (size_t)r * HID + q * 32);   // L0 h0-part
  loadrow<8>(w + 64,  dW1 + (size_t)r * HID + q * 32);   // L1 h0-part
  loadrow<8>(w + 96,  dU1 + (size_t)r * HID + q * 32);   // L1 h1-part
  loadrow<8>(w + 128, fcW + (size_t)fco * HID + q * 32); // fc row (q-half)
  float bs0d = dbi0[r] + dbh0[r];
  float bs1d = dbi1[r] + dbh1[r];
  float fcbt = fcbt_arr[r];
  float fb   = fcb[fco];

  c0 = tanh_full(c0);
  c1 = tanh_full(c1);
  if (tid < 128) {
    float hv = tanh_full(Abuf[128 + tid]);         // tid<64: h0enc; tid>=64: h1enc
    Abuf[(tid < 64) ? 64 + tid : tid - 64] = hv;   // dec layout: H1 @0, H0 @64 (disjoint from reads)
  }
  __syncthreads();

  float pre0h0, pre1h1;
  { // init pre0h0 = dU0 . h0dec(-1) (q-partial)
    const float4* R4 = (const float4*)Abuf;
    const v2f* W0H0 = (const v2f*)(w + 32);
    v2f g0 = {0.f,0.f}, g1 = {0.f,0.f};
#pragma unroll
    for (int k = 0; k < 8; ++k) {
      float4 qv = R4[16 + q * 8 + k]; v2f q0 = {qv.x, qv.y}, q1 = {qv.z, qv.w};
      g0 = __builtin_elementwise_fma(W0H0[2*k],   q0, g0);
      g1 = __builtin_elementwise_fma(W0H0[2*k+1], q1, g1);
    }
    v2f s = g0 + g1; pre0h0 = s.x + s.y;
  }

  // ---------------- phase 2: autoregressive decoder (fused shared-chunk phases) ----------------
  // phase A(t): read h1(t-1) once -> {C0-dot, pre1h1 = dU1-partial, fc}; h0(t) = cell0.
  // phase B(t): read h0(t)   once -> {dW1-dot, pre0h0 = dU0-partial for A(t+1)}; h1(t) = cell1.
  auto dec_phaseA = [&](float* R_, float* W_, int t) {
    const float4* R4 = (const float4*)R_;
    const v2f* W0H1 = (const v2f*)(w);
    const v2f* W1H1 = (const v2f*)(w + 96);
    const v2f* FW   = (const v2f*)(w + 128);
    v2f a0 = {0.f,0.f}, a1 = {0.f,0.f}, e0 = {0.f,0.f}, e1 = {0.f,0.f}, f0 = {0.f,0.f}, f1 = {0.f,0.f};
#pragma unroll
    for (int k = 0; k < 8; ++k) {
      float4 qv = R4[q * 8 + k]; v2f q0 = {qv.x, qv.y}, q1 = {qv.z, qv.w};
      a0 = __builtin_elementwise_fma(W0H1[2*k],   q0, a0);
      a1 = __builtin_elementwise_fma(W0H1[2*k+1], q1, a1);
      e0 = __builtin_elementwise_fma(W1H1[2*k],   q0, e0);
      e1 = __builtin_elementwise_fma(W1H1[2*k+1], q1, e1);
      f0 = __builtin_elementwise_fma(FW[2*k],     q0, f0);
      f1 = __builtin_elementwise_fma(FW[2*k+1],   q1, f1);
    }
    v2f se = e0 + e1; pre1h1 = se.x + se.y;
    v2f sa = a0 + a1;
    float p0 = dpp_add<0xB1>(sa.x + sa.y + pre0h0) + bs0d + fcbt;
    float h0v = cell_update(p0, gsc, gscl, gof, c0);
    if (l8 == 0) W_[64 + j] = h0v;
    v2f sf = f0 + f1;
    float s = dpp_add<0xB1>(sf.x + sf.y);
    if (fcwr) outb[(size_t)(t - 1) * DOUT + fco] = s + fb;   // pred(t-1)
    bar_lds();
  };
  auto dec_phaseB = [&](float* W_) {
    const float4* W4 = (const float4*)W_;
    const v2f* W1H0 = (const v2f*)(w + 64);
    const v2f* W0H0 = (const v2f*)(w + 32);
    v2f b0 = {0.f,0.f}, b1 = {0.f,0.f}, g0 = {0.f,0.f}, g1 = {0.f,0.f};
#pragma unroll
    for (int k = 0; k < 8; ++k) {
      float4 qv = W4[16 + q * 8 + k]; v2f q0 = {qv.x, qv.y}, q1 = {qv.z, qv.w};
      b0 = __builtin_elementwise_fma(W1H0[2*k],   q0, b0);
      b1 = __builtin_elementwise_fma(W1H0[2*k+1], q1, b1);
      g0 = __builtin_elementwise_fma(W0H0[2*k],   q0, g0);
      g1 = __builtin_elementwise_fma(W0H0[2*k+1], q1, g1);
    }
    v2f sb = b0 + b1;
    float p1 = dpp_add<0xB1>(sb.x + sb.y + pre1h1) + bs1d;
    float h1v = cell_update(p1, gsc, gscl, gof, c1);
    if (l8 == 0) W_[j] = h1v;
    v2f sg = g0 + g1; pre0h0 = sg.x + sg.y;       // for next phase A
    bar_lds();
  };

  // step 0 peeled: x(0)=0 -> no C0 term, no fcbt, no fc output; pre1h1 from h1dec(-1)
  {
    const float4* R4 = (const float4*)Abuf;
    const v2f* W1H1 = (const v2f*)(w + 96);
    v2f e0 = {0.f,0.f}, e1 = {0.f,0.f};
#pragma unroll
    for (int k = 0; k < 8; ++k) {
      float4 qv = R4[q * 8 + k]; v2f q0 = {qv.x, qv.y}, q1 = {qv.z, qv.w};
      e0 = __builtin_elementwise_fma(W1H1[2*k],   q0, e0);
      e1 = __builtin_elementwise_fma(W1H1[2*k+1], q1, e1);
    }
    v2f se = e0 + e1; pre1h1 = se.x + se.y;
    float p0 = dpp_add<0xB1>(pre0h0) + bs0d;
    float h0v = cell_update(p0, gsc, gscl, gof, c0);
    if (l8 == 0) Bbuf[64 + j] = h0v;
    bar_lds();
    dec_phaseB(Bbuf);
  }
#pragma unroll 1
  for (int t = 1; t < 1023; t += 2) {
    dec_phaseA(Bbuf, Abuf, t);     dec_phaseB(Abuf);
    dec_phaseA(Abuf, Bbuf, t + 1); dec_phaseB(Bbuf);
  }
  dec_phaseA(Bbuf, Abuf, 1023);    dec_phaseB(Abuf);

  // epilogue: pred(1023) from h1(1023) @ Abuf.H1
  {
    const float4* R4 = (const float4*)Abuf;
    const v2f* FW = (const v2f*)(w + 128);
    v2f f0 = {0.f,0.f}, f1 = {0.f,0.f};
#pragma unroll
    for (int k = 0; k < 8; ++k) {
      float4 qv = R4[q * 8 + k]; v2f q0 = {qv.x, qv.y}, q1 = {qv.z, qv.w};
      f0 = __builtin_elementwise_fma(FW[2*k],   q0, f0);
      f1 = __builtin_elementwise_fma(FW[2*k+1], q1, f1);
    }
    v2f sf = f0 + f1;
    float s = dpp_add<0xB1>(sf.x + sf.y);
    if (fcwr) outb[(size_t)(T_SEQ - 1) * DOUT + fco] = s + fb;
  }
}

extern "C" void kernel_launch(void* const* d_in, const int* in_sizes, int n_in,
                              void* d_out, int out_size, void* d_ws, size_t ws_size,
                              hipStream_t stream) {
  (void)in_sizes; (void)n_in; (void)ws_size; (void)out_size;
  const float* x    = (const float*)d_in[0];
  const float* eW0  = (const float*)d_in[1];
  const float* eU0  = (const float*)d_in[2];
  const float* ebi0 = (const float*)d_in[3];
  const float* ebh0 = (const float*)d_in[4];
  const float* eW1  = (const float*)d_in[5];
  const float* eU1  = (const float*)d_in[6];
  const float* ebi1 = (const float*)d_in[7];
  const float* ebh1 = (const float*)d_in[8];
  const float* dW0  = (const float*)d_in[9];
  const float* dU0  = (const float*)d_in[10];
  const float* dbi0 = (const float*)d_in[11];
  const float* dbh0 = (const float*)d_in[12];
  const float* dW1  = (const float*)d_in[13];
  const float* dU1  = (const float*)d_in[14];
  const float* dbi1 = (const float*)d_in[15];
  const float* dbh1 = (const float*)d_in[16];
  const float* fcW  = (const float*)d_in[17];
  const float* fcb  = (const float*)d_in[18];
  float* ws  = (float*)d_ws;
  float* out = (float*)d_out;

  hipLaunchKernelGGL(prep_kernel, dim3(256), dim3(64), 0, stream, dW0, fcW, fcb, ws);
  hipLaunchKernelGGL(lstm_ae_kernel, dim3(NBATCH), dim3(512), 0, stream,
                     x, eW0, eU0, ebi0, ebh0, eW1, eU1, ebi1, ebh1,
                     dW0, dU0, dbi0, dbh0, dW1, dU1, dbi1, dbh1,
                     fcW, fcb, ws, out);
}

// Round 7
// 1783.044 us; speedup vs baseline: 2.5997x; 1.1371x over previous
//
#include <hip/hip_runtime.h>

#define T_SEQ 1024
#define NBATCH 256
#define DIN 128
#define HID 64
#define DOUT 128

// ---------------- LDS layouts (512 thr, fused shared-chunk reads, single copies) ----------------
// Encoder buffer (256 floats): X @0(128) | H0 @128(64) | H1 @192(64)
// Decoder overlay (128 floats): H1 @0(64) | H0 @64(64)
// K-split is INTERLEAVED by f4: thread half q owns f4 elements {2i+q} of each chunk.
// Per ds_read_b128: even lanes at banks 8i..8i+3, odd at 8i+4..8i+7 -> conflict-free.
#define TWO_LOG2E 2.8853900817779268f   // 2*log2(e)

typedef float v2f __attribute__((ext_vector_type(2)));

__device__ __forceinline__ float rcp_f(float x) { return __builtin_amdgcn_rcpf(x); }

__device__ __forceinline__ float exp2_f(float x) {
#if __has_builtin(__builtin_amdgcn_exp2f)
  return __builtin_amdgcn_exp2f(x);
#else
  return exp2f(x);
#endif
}

// tanh(x) with pre-scaled argument y = x*TWO_LOG2E:  tanh = 1 - 2/(1+2^y); inf-safe
__device__ __forceinline__ float tanh_pre(float y) {
  float m = exp2_f(y);
  return fmaf(-2.0f, rcp_f(1.0f + m), 1.0f);
}
__device__ __forceinline__ float tanh_full(float x) { return tanh_pre(x * TWO_LOG2E); }

// quad-perm DPP butterfly add (lane^1: 0xB1) on the VALU pipe
template<int CTRL>
__device__ __forceinline__ float dpp_add(float v) {
  int p = __builtin_amdgcn_update_dpp(0, __float_as_int(v), CTRL, 0xF, 0xF, true);
  return v + __int_as_float(p);
}

// DPP mov row_shl:N (0x100|N): dst lane i <- src lane i+N within 16-lane row
template<int CTRL>
__device__ __forceinline__ float dpp_mov(float v) {
  int p = __builtin_amdgcn_update_dpp(0, __float_as_int(v), CTRL, 0xF, 0xF, true);
  return __int_as_float(p);
}

// LDS-only barrier: do NOT drain vmcnt (x prefetch loads / out stores stay in flight).
__device__ __forceinline__ void bar_lds() {
  asm volatile("s_waitcnt lgkmcnt(0)\n\ts_barrier" ::: "memory");
}

// Interleaved weight load: thread's w f4-slot i <- row f4 element (2i+q).
template<int N4>
__device__ __forceinline__ void loadrow_il(float* w, const float* p, int q) {
#pragma unroll
  for (int i = 0; i < N4; ++i) {
    float4 v = ((const float4*)p)[2 * i + q];
    w[4*i+0] = v.x; w[4*i+1] = v.y; w[4*i+2] = v.z; w[4*i+3] = v.w;
  }
}

// Lane map: q = tid&1 (k-interleave), g = (tid>>1)&3 (gate i,f,g,o), j = tid>>3 (unit).
// After the q-butterfly (xor1), 8-lane group holds: lanes 0,1=i; 2,3=f; 4,5=g~; 6,7=o.
// Gather f/g~/o into lanes 0,1 with row_shl:2/4/6. c/h valid on lanes 0,1 of each group.
__device__ __forceinline__ float cell_update(float pre, float gsc, float gscl, float gof, float& c) {
  float a  = fmaf(gsc, tanh_pre(pre * gscl), gof);  // sigmoid for i,f,o ; tanh for g
  float f_s = dpp_mov<0x102>(a);
  float g_t = dpp_mov<0x104>(a);
  float o_s = dpp_mov<0x106>(a);
  c = fmaf(f_s, c, a * g_t);
  return o_s * tanh_full(c);
}

// ---------------- prep kernel: C0 = dWih0 @ fcW  [256x64], fcbt = dWih0 @ fcb ----------------
__global__ void prep_kernel(const float* __restrict__ dWih0,
                            const float* __restrict__ fcW,
                            const float* __restrict__ fcb,
                            float* __restrict__ ws) {
  const int r = (int)blockIdx.x;           // 256 blocks
  const int jj = (int)threadIdx.x;         // 64 threads
  const float* wr = dWih0 + (size_t)r * DIN;
  float acc = 0.f;
  for (int o = 0; o < DIN; ++o) acc = fmaf(wr[o], fcW[(size_t)o * HID + jj], acc);
  ws[(size_t)r * HID + jj] = acc;
  if (jj == 0) {
    float a = 0.f;
    for (int o = 0; o < DIN; ++o) a = fmaf(wr[o], fcb[o], a);
    ws[256 * HID + r] = a;
  }
}

// ---------------- main persistent kernel: 1 block / batch element, 512 threads ----------------
__global__ __launch_bounds__(512, 2) void lstm_ae_kernel(
    const float* __restrict__ x,
    const float* __restrict__ eW0, const float* __restrict__ eU0,
    const float* __restrict__ ebi0, const float* __restrict__ ebh0,
    const float* __restrict__ eW1, const float* __restrict__ eU1,
    const float* __restrict__ ebi1, const float* __restrict__ ebh1,
    const float* __restrict__ dW0, const float* __restrict__ dU0,
    const float* __restrict__ dbi0, const float* __restrict__ dbh0,
    const float* __restrict__ dW1, const float* __restrict__ dU1,
    const float* __restrict__ dbi1, const float* __restrict__ dbh1,
    const float* __restrict__ fcW, const float* __restrict__ fcb,
    const float* __restrict__ ws,
    float* __restrict__ out)
{
  __shared__ __align__(16) float Abuf[256];
  __shared__ __align__(16) float Bbuf[256];

  const int tid = (int)threadIdx.x;
  const int b   = (int)blockIdx.x;
  const int q   = tid & 1;
  const int g   = (tid >> 1) & 3;
  const int j   = tid >> 3;
  const int r   = g * HID + j;
  const int l8  = tid & 7;
  const int fco = (tid >> 1) & 127;                    // fc output row (2x replicated)
  const bool fcwr = ((tid & 1) == 0) && (tid < 256);   // unique fc writer lanes

  const float gsc  = (g == 2) ? 1.0f : 0.5f;
  const float gof  = (g == 2) ? 0.0f : 0.5f;
  const float gscl = gsc * TWO_LOG2E;

  float w[160];

  // ---------------- encoder weights (interleaved q-split of each K-chunk, 1 row/thread) ----------------
  loadrow_il<16>(w,       eW0 + (size_t)r * DIN, q);   // L0 x-part   (64 floats)
  loadrow_il<8> (w + 64,  eU0 + (size_t)r * HID, q);   // L0 h0-part  (32)
  loadrow_il<8> (w + 96,  eW1 + (size_t)r * HID, q);   // L1 h0-part  (32)
  loadrow_il<8> (w + 128, eU1 + (size_t)r * HID, q);   // L1 h1-part  (32)
  float bs0 = ebi0[r] + ebh0[r];
  float bs1 = ebi1[r] + ebh1[r];

  const float* xb = x + (size_t)b * (T_SEQ * DIN);
  float* outb     = out + (size_t)b * (T_SEQ * DOUT);

  // init: A = [x0 | h0(-1)=0 | h1(-2)=0]; B.H1 = h1(-1) = 0
  if (tid < 32) ((float4*)Abuf)[tid] = ((const float4*)xb)[tid];
  if (tid >= 128 && tid < 256) Abuf[tid] = 0.f;
  if (tid >= 192 && tid < 256) Bbuf[tid] = 0.f;
  float4 xcar{};
  if (tid < 32) xcar = ((const float4*)(xb + DIN))[tid];   // x(1) in flight
  float c0 = 0.f, c1 = 0.f;
  __syncthreads();

  // ---------------- phase 1: layer-skewed fused encoder (ONE barrier per phase) ----------------
  auto enc_phase = [&](float* R, float* W, int t) {
    if (tid < 32 && t + 1 < T_SEQ) ((float4*)W)[tid] = xcar;       // stage x(t+1) (vmcnt slack: 1 phase)
    if (tid < 32 && t + 2 < T_SEQ)
      xcar = ((const float4*)(xb + (size_t)(t + 2) * DIN))[tid];   // issue x(t+2)
    const float4* R4 = (const float4*)R;
    const v2f* wx  = (const v2f*)(w);
    const v2f* wh  = (const v2f*)(w + 64);
    const v2f* w1h = (const v2f*)(w + 96);
    const v2f* w1g = (const v2f*)(w + 128);
    v2f p0a = {0.f,0.f}, p0b = {0.f,0.f}, p1a = {0.f,0.f}, p1b = {0.f,0.f};
#pragma unroll
    for (int k = 0; k < 16; ++k) {                                  // x chunk (L0 only), f4 elem 2k+q
      float4 qv = R4[2 * k + q]; v2f q0 = {qv.x, qv.y}, q1 = {qv.z, qv.w};
      p0a = __builtin_elementwise_fma(wx[2*k],   q0, p0a);
      p0b = __builtin_elementwise_fma(wx[2*k+1], q1, p0b);
    }
#pragma unroll
    for (int k = 0; k < 8; ++k) {                                   // h0 chunk (L0 AND L1, shared read)
      float4 qv = R4[32 + 2 * k + q]; v2f q0 = {qv.x, qv.y}, q1 = {qv.z, qv.w};
      p0a = __builtin_elementwise_fma(wh[2*k],    q0, p0a);
      p0b = __builtin_elementwise_fma(wh[2*k+1],  q1, p0b);
      p1a = __builtin_elementwise_fma(w1h[2*k],   q0, p1a);
      p1b = __builtin_elementwise_fma(w1h[2*k+1], q1, p1b);
    }
#pragma unroll
    for (int k = 0; k < 8; ++k) {                                   // h1 chunk (L1 only)
      float4 qv = R4[48 + 2 * k + q]; v2f q0 = {qv.x, qv.y}, q1 = {qv.z, qv.w};
      p1a = __builtin_elementwise_fma(w1g[2*k],   q0, p1a);
      p1b = __builtin_elementwise_fma(w1g[2*k+1], q1, p1b);
    }
    v2f s0 = p0a + p0b, s1 = p1a + p1b;
    float p0 = dpp_add<0xB1>(s0.x + s0.y) + bs0;
    float p1 = dpp_add<0xB1>(s1.x + s1.y) + bs1;
    float h0v = cell_update(p0, gsc, gscl, gof, c0);
    float c1n = c1;
    float h1v = cell_update(p1, gsc, gscl, gof, c1n);
    if (l8 == 0) W[128 + j] = h0v;                 // h0(t)
    if (t > 0) {                                   // t=0: h1(-1)/c1 stay at zero init
      c1 = c1n;
      if (l8 == 1) W[192 + j] = h1v;               // h1(t-1)
    }
    bar_lds();
  };

#pragma unroll 1
  for (int t = 0; t < T_SEQ; t += 2) {
    enc_phase(Abuf, Bbuf, t);
    enc_phase(Bbuf, Abuf, t + 1);
  }
  // encoder epilogue: h1(1023) from A = [h0(1023) | h1(1022)]
  {
    const float4* R4 = (const float4*)Abuf;
    const v2f* w1h = (const v2f*)(w + 96);
    const v2f* w1g = (const v2f*)(w + 128);
    v2f p1a = {0.f,0.f}, p1b = {0.f,0.f};
#pragma unroll
    for (int k = 0; k < 8; ++k) {
      float4 qv = R4[32 + 2 * k + q]; v2f q0 = {qv.x, qv.y}, q1 = {qv.z, qv.w};
      p1a = __builtin_elementwise_fma(w1h[2*k],   q0, p1a);
      p1b = __builtin_elementwise_fma(w1h[2*k+1], q1, p1b);
    }
#pragma unroll
    for (int k = 0; k < 8; ++k) {
      float4 qv = R4[48 + 2 * k + q]; v2f q0 = {qv.x, qv.y}, q1 = {qv.z, qv.w};
      p1a = __builtin_elementwise_fma(w1g[2*k],   q0, p1a);
      p1b = __builtin_elementwise_fma(w1g[2*k+1], q1, p1b);
    }
    v2f s1 = p1a + p1b;
    float p1 = dpp_add<0xB1>(s1.x + s1.y) + bs1;
    float h1v = cell_update(p1, gsc, gscl, gof, c1);
    bar_lds();                                     // reads of old h1 slot done before overwrite
    if (l8 == 0) Abuf[192 + j] = h1v;
  }
  __syncthreads();

  // ---------------- transition: decoder weights + state re-layout ----------------
  const float* C0 = ws;
  const float* fcbt_arr = ws + 256 * HID;
  loadrow_il<8>(w,       C0  + (size_t)r * HID, q);    // L0 h1-part (composite C0)
  loadrow_il<8>(w + 32,  dU0 + (size_t)r * HID, q);    // L0 h0-part
  loadrow_il<8>(w + 64,  dW1 + (size_t)r * HID, q);    // L1 h0-part
  loadrow_il<8>(w + 96,  dU1 + (size_t)r * HID, q);    // L1 h1-part
  loadrow_il<8>(w + 128, fcW + (size_t)fco * HID, q);  // fc row
  float bs0d = dbi0[r] + dbh0[r];
  float bs1d = dbi1[r] + dbh1[r];
  float fcbt = fcbt_arr[r];
  float fb   = fcb[fco];

  c0 = tanh_full(c0);
  c1 = tanh_full(c1);
  if (tid < 128) {
    float hv = tanh_full(Abuf[128 + tid]);         // tid<64: h0enc; tid>=64: h1enc
    Abuf[(tid < 64) ? 64 + tid : tid - 64] = hv;   // dec layout: H1 @0, H0 @64 (disjoint from reads)
  }
  __syncthreads();

  float pre0h0, pre1h1;
  { // init pre0h0 = dU0 . h0dec(-1) (q-partial)
    const float4* R4 = (const float4*)Abuf;
    const v2f* W0H0 = (const v2f*)(w + 32);
    v2f g0 = {0.f,0.f}, g1 = {0.f,0.f};
#pragma unroll
    for (int k = 0; k < 8; ++k) {
      float4 qv = R4[16 + 2 * k + q]; v2f q0 = {qv.x, qv.y}, q1 = {qv.z, qv.w};
      g0 = __builtin_elementwise_fma(W0H0[2*k],   q0, g0);
      g1 = __builtin_elementwise_fma(W0H0[2*k+1], q1, g1);
    }
    v2f s = g0 + g1; pre0h0 = s.x + s.y;
  }

  // ---------------- phase 2: autoregressive decoder (fused shared-chunk phases) ----------------
  // phase A(t): read h1(t-1) once -> {C0-dot, pre1h1 = dU1-partial, fc}; h0(t) = cell0.
  // phase B(t): read h0(t)   once -> {dW1-dot, pre0h0 = dU0-partial for A(t+1)}; h1(t) = cell1.
  auto dec_phaseA = [&](float* R_, float* W_, int t) {
    const float4* R4 = (const float4*)R_;
    const v2f* W0H1 = (const v2f*)(w);
    const v2f* W1H1 = (const v2f*)(w + 96);
    const v2f* FW   = (const v2f*)(w + 128);
    v2f a0 = {0.f,0.f}, a1 = {0.f,0.f}, e0 = {0.f,0.f}, e1 = {0.f,0.f}, f0 = {0.f,0.f}, f1 = {0.f,0.f};
#pragma unroll
    for (int k = 0; k < 8; ++k) {
      float4 qv = R4[2 * k + q]; v2f q0 = {qv.x, qv.y}, q1 = {qv.z, qv.w};
      a0 = __builtin_elementwise_fma(W0H1[2*k],   q0, a0);
      a1 = __builtin_elementwise_fma(W0H1[2*k+1], q1, a1);
      e0 = __builtin_elementwise_fma(W1H1[2*k],   q0, e0);
      e1 = __builtin_elementwise_fma(W1H1[2*k+1], q1, e1);
      f0 = __builtin_elementwise_fma(FW[2*k],     q0, f0);
      f1 = __builtin_elementwise_fma(FW[2*k+1],   q1, f1);
    }
    v2f se = e0 + e1; pre1h1 = se.x + se.y;
    v2f sa = a0 + a1;
    float p0 = dpp_add<0xB1>(sa.x + sa.y + pre0h0) + bs0d + fcbt;
    float h0v = cell_update(p0, gsc, gscl, gof, c0);
    if (l8 == 0) W_[64 + j] = h0v;
    v2f sf = f0 + f1;
    float s = dpp_add<0xB1>(sf.x + sf.y);
    if (fcwr) outb[(size_t)(t - 1) * DOUT + fco] = s + fb;   // pred(t-1)
    bar_lds();
  };
  auto dec_phaseB = [&](float* W_) {
    const float4* W4 = (const float4*)W_;
    const v2f* W1H0 = (const v2f*)(w + 64);
    const v2f* W0H0 = (const v2f*)(w + 32);
    v2f b0 = {0.f,0.f}, b1 = {0.f,0.f}, g0 = {0.f,0.f}, g1 = {0.f,0.f};
#pragma unroll
    for (int k = 0; k < 8; ++k) {
      float4 qv = W4[16 + 2 * k + q]; v2f q0 = {qv.x, qv.y}, q1 = {qv.z, qv.w};
      b0 = __builtin_elementwise_fma(W1H0[2*k],   q0, b0);
      b1 = __builtin_elementwise_fma(W1H0[2*k+1], q1, b1);
      g0 = __builtin_elementwise_fma(W0H0[2*k],   q0, g0);
      g1 = __builtin_elementwise_fma(W0H0[2*k+1], q1, g1);
    }
    v2f sb = b0 + b1;
    float p1 = dpp_add<0xB1>(sb.x + sb.y + pre1h1) + bs1d;
    float h1v = cell_update(p1, gsc, gscl, gof, c1);
    if (l8 == 0) W_[j] = h1v;
    v2f sg = g0 + g1; pre0h0 = sg.x + sg.y;       // for next phase A
    bar_lds();
  };

  // step 0 peeled: x(0)=0 -> no C0 term, no fcbt, no fc output; pre1h1 from h1dec(-1)
  {
    const float4* R4 = (const float4*)Abuf;
    const v2f* W1H1 = (const v2f*)(w + 96);
    v2f e0 = {0.f,0.f}, e1 = {0.f,0.f};
#pragma unroll
    for (int k = 0; k < 8; ++k) {
      float4 qv = R4[2 * k + q]; v2f q0 = {qv.x, qv.y}, q1 = {qv.z, qv.w};
      e0 = __builtin_elementwise_fma(W1H1[2*k],   q0, e0);
      e1 = __builtin_elementwise_fma(W1H1[2*k+1], q1, e1);
    }
    v2f se = e0 + e1; pre1h1 = se.x + se.y;
    float p0 = dpp_add<0xB1>(pre0h0) + bs0d;
    float h0v = cell_update(p0, gsc, gscl, gof, c0);
    if (l8 == 0) Bbuf[64 + j] = h0v;
    bar_lds();
    dec_phaseB(Bbuf);
  }
#pragma unroll 1
  for (int t = 1; t < 1023; t += 2) {
    dec_phaseA(Bbuf, Abuf, t);     dec_phaseB(Abuf);
    dec_phaseA(Abuf, Bbuf, t + 1); dec_phaseB(Bbuf);
  }
  dec_phaseA(Bbuf, Abuf, 1023);    dec_phaseB(Abuf);

  // epilogue: pred(1023) from h1(1023) @ Abuf.H1
  {
    const float4* R4 = (const float4*)Abuf;
    const v2f* FW = (const v2f*)(w + 128);
    v2f f0 = {0.f,0.f}, f1 = {0.f,0.f};
#pragma unroll
    for (int k = 0; k < 8; ++k) {
      float4 qv = R4[2 * k + q]; v2f q0 = {qv.x, qv.y}, q1 = {qv.z, qv.w};
      f0 = __builtin_elementwise_fma(FW[2*k],   q0, f0);
      f1 = __builtin_elementwise_fma(FW[2*k+1], q1, f1);
    }
    v2f sf = f0 + f1;
    float s = dpp_add<0xB1>(sf.x + sf.y);
    if (fcwr) outb[(size_t)(T_SEQ - 1) * DOUT + fco] = s + fb;
  }
}

extern "C" void kernel_launch(void* const* d_in, const int* in_sizes, int n_in,
                              void* d_out, int out_size, void* d_ws, size_t ws_size,
                              hipStream_t stream) {
  (void)in_sizes; (void)n_in; (void)ws_size; (void)out_size;
  const float* x    = (const float*)d_in[0];
  const float* eW0  = (const float*)d_in[1];
  const float* eU0  = (const float*)d_in[2];
  const float* ebi0 = (const float*)d_in[3];
  const float* ebh0 = (const float*)d_in[4];
  const float* eW1  = (const float*)d_in[5];
  const float* eU1  = (const float*)d_in[6];
  const float* ebi1 = (const float*)d_in[7];
  const float* ebh1 = (const float*)d_in[8];
  const float* dW0  = (const float*)d_in[9];
  const float* dU0  = (const float*)d_in[10];
  const float* dbi0 = (const float*)d_in[11];
  const float* dbh0 = (const float*)d_in[12];
  const float* dW1  = (const float*)d_in[13];
  const float* dU1  = (const float*)d_in[14];
  const float* dbi1 = (const float*)d_in[15];
  const float* dbh1 = (const float*)d_in[16];
  const float* fcW  = (const float*)d_in[17];
  const float* fcb  = (const float*)d_in[18];
  float* ws  = (float*)d_ws;
  float* out = (float*)d_out;

  hipLaunchKernelGGL(prep_kernel, dim3(256), dim3(64), 0, stream, dW0, fcW, fcb, ws);
  hipLaunchKernelGGL(lstm_ae_kernel, dim3(NBATCH), dim3(512), 0, stream,
                     x, eW0, eU0, ebi0, ebh0, eW1, eU1, ebi1, ebh1,
                     dW0, dU0, dbi0, dbh0, dW1, dU1, dbi1, dbh1,
                     fcW, fcb, ws, out);
}